// Round 8
// baseline (402.333 us; speedup 1.0000x reference)
//
#include <hip/hip_runtime.h>

#define N_NODES 20000
#define NPAIRS  10000
#define N_EDGES 320000
#define CAP     48
#define KN      15
#define GRID_MAIN 2500

typedef _Float16 half_t;
typedef _Float16 half2_t __attribute__((ext_vector_type(2)));
typedef float f32x2 __attribute__((ext_vector_type(2)));

// params float-index layout
#define P_ALPHA 0
#define P_BETA  1
#define P_IEPS2 2
#define P_EPS   3
#define P_HC2   16
#define P_RSC2  216
#define P_F1    316

// workspace byte offsets (single contiguous zero region up front)
#define OFF_CNT    0u             // 80 KB  (zeroed)
#define OFF_WCT    80000u         // 80 KB  (zeroed)
#define OFF_STATS  160000u        // (unused now; kept for layout stability)
#define OFF_FLAG   160520u        // (zeroed)
#define OFF_PAD    160524u        // (zeroed)
#define MEMSET_LEN 160528u        // one memset covers cnt+wct+..+flag+pad
#define OFF_NBC    160528u        // 80 KB
#define OFF_S2X    240528u        // 80 KB (written before read; no zeroing)
#define OFF_NEIGH  320528u        // 1.2 MB
#define OFF_BUF    1520528u       // 3.84 MB edge slots; xh (2.56 MB) overwrites
#define OFF_PARAMS 5360528u       // 1.7 KB
#define OFF_PART   5362240u       // 1000 x 65 float partials (260 KB)

// tf_l per-template stride (halfs): dword stride 324 = 4 (mod 32)
#define TF_STRIDE 648

// ---- 16-lane reduction via DPP row_ror adds: pure VALU ----
template<int CTRL>
__device__ __forceinline__ float dpp_add(float v) {
  int s = __builtin_bit_cast(int, v);
  int r = __builtin_amdgcn_update_dpp(0, s, CTRL, 0xF, 0xF, true);
  return v + __builtin_bit_cast(float, r);
}
__device__ __forceinline__ float sum16(float v) {
  v = dpp_add<0x128>(v);   // row_ror:8
  v = dpp_add<0x124>(v);   // row_ror:4
  v = dpp_add<0x122>(v);   // row_ror:2
  v = dpp_add<0x121>(v);   // row_ror:1
  return v;
}
// ds_swizzle imm BitMode 0x010: new_lane = lane&0x10 -> broadcast k=0 of group
__device__ __forceinline__ float bcast16(float v) {
  return __builtin_bit_cast(float,
      __builtin_amdgcn_ds_swizzle(__builtin_bit_cast(int, v), 0x010));
}
__device__ __forceinline__ float fdot2(half2_t a, half2_t b, float c) {
  return __builtin_amdgcn_fdot2(a, b, c, false);
}
__device__ __forceinline__ half2_t h2(unsigned int u) {
  return __builtin_bit_cast(half2_t, u);
}
// force a wave-uniform float into an SGPR
__device__ __forceinline__ float sgpr(float v) {
  return __builtin_bit_cast(float,
      __builtin_amdgcn_readfirstlane(__builtin_bit_cast(int, v)));
}
// ---- packed fp32 VALU ops: 2 independent IEEE fma/mul per instruction ----
__device__ __forceinline__ f32x2 pk_fma(f32x2 a, f32x2 b, f32x2 c) {
  f32x2 d;
  asm("v_pk_fma_f32 %0, %1, %2, %3" : "=v"(d) : "v"(a), "v"(b), "v"(c));
  return d;
}
__device__ __forceinline__ f32x2 pk_mul(f32x2 a, f32x2 b) {
  f32x2 d;
  asm("v_pk_mul_f32 %0, %1, %2" : "=v"(d) : "v"(a), "v"(b));
  return d;
}

// ---------------- kernel 1: scatter edge ids per source node ----------------
__global__ void k_scatter(const int* __restrict__ ei, int* __restrict__ cnt,
                          int* __restrict__ buf) {
  int e = blockIdx.x * blockDim.x + threadIdx.x;
  if (e >= N_EDGES) return;
  int s = ei[e];
  int slot = atomicAdd(&cnt[s], 1);
  if (slot < CAP) buf[s * CAP + slot] = e;
}

// ---- kernel 2: select 15 smallest edge ids, scatter neighbor weights ------
#define SS_BLOCKS 2500
__global__ void __launch_bounds__(256)
k_sel(const int* __restrict__ ei, const int* __restrict__ cnt,
      const int* __restrict__ buf, int* __restrict__ nbc_g,
      int* __restrict__ neigh, int* __restrict__ wct,
      int* __restrict__ padc) {
  const int lane = threadIdx.x & 63;
  const int wid = threadIdx.x >> 6;
  const int* dst = ei + N_EDGES;
  __shared__ int padsh;
  if (threadIdx.x == 0) padsh = 0;
  __syncthreads();
  int padacc = 0;

  for (int w = blockIdx.x * 4 + wid; w < N_NODES; w += SS_BLOCKS * 4) {
    int c = cnt[w];
    int cc = c < CAP ? c : CAP;
    int e = (lane < cc) ? buf[w * CAP + lane] : 0x7fffffff;
    int nb = c < KN ? c : KN;
    bool sel;
    if (cc <= KN) {
      sel = lane < cc;
    } else {
      int rank = 0;
      for (int j = 0; j < cc; j++) {      // cc is wave-uniform
        int ej = __shfl(e, j);
        rank += (ej < e) ? 1 : 0;
      }
      sel = (e != 0x7fffffff) && (rank < KN);  // distinct ids -> exactly 15
    }
    unsigned long long mask = __ballot(sel);
    if (sel) {
      int pos = __popcll(mask & ((1ull << lane) - 1ull));
      int d = dst[e];
      neigh[w * KN + pos] = d;
      atomicAdd(&wct[d], 1);             // neighbor-occurrence weight
    }
    if (lane == 0) { nbc_g[w] = nb; padacc += KN - nb; }
  }
  if (lane == 0 && padacc) atomicAdd(&padsh, padacc);
  __syncthreads();
  if (threadIdx.x == 0 && padsh) atomicAdd(padc, padsh);
}

// ---- kernel 2.5: ONE coalesced pass over x ---------------------------------
// Produces xh (f16 RTNE), s2xh, weighted eps-stats via per-block float
// partials (NO atomic contention; fixed-order double sum in the last block),
// then finalizes params. PB=1000 -> 4000 waves, 5 rows/wave.
#define PB 1000
__global__ void __launch_bounds__(256)
k_pass(const float* __restrict__ x, half_t* __restrict__ xh,
       const int* __restrict__ wct, const int* __restrict__ padc,
       float* __restrict__ s2xh, float* __restrict__ part,
       int* __restrict__ flag, const float* __restrict__ tf,
       const float* __restrict__ c2, const float* __restrict__ alpha0,
       float* __restrict__ params) {
  const int lane = threadIdx.x & 63;
  const int wid = threadIdx.x >> 6;
  const int tid = threadIdx.x;
  const int pad = *padc;
  float accx = 0.f, acc2 = 0.f;

  for (int n = blockIdx.x * 4 + wid; n < N_NODES; n += PB * 4) {
    float xv = x[n * 64 + lane];
    half_t hv = (half_t)xv;              // RTNE, matches k_main path
    xh[n * 64 + lane] = hv;
    float hf = (float)hv;
    float sq = hf * hf;
#pragma unroll
    for (int off = 32; off > 0; off >>= 1) sq += __shfl_xor(sq, off, 64);
    if (lane == 0) s2xh[n] = sq;
    float wt = (float)(1 + wct[n] + ((n == 0) ? pad : 0));
    accx = fmaf(wt, xv, accx);
    acc2 = fmaf(wt, xv * xv, acc2);
  }

  // ---- block reduction -> per-block partial row (no atomics) ----
#pragma unroll
  for (int off = 32; off > 0; off >>= 1) acc2 += __shfl_xor(acc2, off, 64);
  __shared__ float redx[4][64];
  __shared__ float red2[4];
  __shared__ int lastsh;
  redx[wid][lane] = accx;
  if (lane == 0) red2[wid] = acc2;
  __syncthreads();
  if (tid < 64) {
    float s = redx[0][tid] + redx[1][tid] + redx[2][tid] + redx[3][tid];
    part[blockIdx.x * 65 + 1 + tid] = s;
  }
  if (tid == 0)
    part[blockIdx.x * 65] = red2[0] + red2[1] + red2[2] + red2[3];
  __syncthreads();
  if (tid == 0) {
    __threadfence();
    int old = atomicAdd(flag, 1);
    lastsh = (old == PB - 1) ? 1 : 0;
  }
  __syncthreads();
  if (!lastsh) return;
  __threadfence();   // acquire: all blocks' partial writes visible
  // ------- finalize (runs once, in the last-finishing block) -------
  __shared__ float sh[4];
  if (tid < 64) {
    // per-feature weighted sum over all block partials (2-way pipelined)
    double sx0 = 0.0, sx1 = 0.0;
    for (int b = 0; b < PB; b += 2) {
      sx0 += (double)part[b * 65 + 1 + tid];
      sx1 += (double)part[(b + 1) * 65 + 1 + tid];
    }
    double sx = sx0 + sx1;
    // |x|^2 total: lanes stride over blocks, then 64-lane reduce
    double asub = 0.0;
    for (int b = tid; b < PB; b += 64) asub += (double)part[b * 65];
#pragma unroll
    for (int off = 32; off > 0; off >>= 1) asub += __shfl_xor(asub, off, 64);

    float s = 0.f, s2 = 0.f;
    for (int tm = 0; tm < 100; tm++) { float v = tf[tm * 64 + tid]; s += v; s2 += v * v; }
    double inv16N = 1.0 / (double)(N_NODES * 16);
    double cross = (sx * inv16N) * ((double)s / 100.0);
    double B = (double)s2 / 100.0;
    double term = B - 2.0 * cross;
#pragma unroll
    for (int off = 32; off > 0; off >>= 1) term += __shfl_xor(term, off, 64);
    if (tid == 0) {
      double A = asub * inv16N;
      double meanM = A + term;
      float eps = (float)(0.05 * meanM) + 1e-6f;
      float a0 = alpha0[0];
      float alpha = 1.f / (1.f + expf(-a0));
      params[P_ALPHA] = alpha;
      params[P_BETA]  = 1.f - alpha;
      params[P_IEPS2] = 1.4426950408889634f / eps;
      params[P_EPS]   = eps;
      sh[0] = alpha; sh[1] = 1.f - alpha; sh[2] = 1.4426950408889634f / eps;
    }
  }
  __syncthreads();
  if (tid < 100) {
    float alpha = sh[0], beta = sh[1], ieps2 = sh[2];
    int t = tid / 10, mm = tid % 10;
    float h = 0.f;
    for (int r = 0; r < 10; r++) { float cv = c2[t * 100 + mm * 10 + r]; h += cv * cv; }
    float hc2v = 0.1f * h;
    params[P_HC2 + tid] = hc2v;
    float s2 = 0.f;
    for (int f = 0; f < 64; f++) { float v = tf[tid * 64 + f]; s2 += v * v; }
    float rs = 0.f;
    for (int m2_ = 0; m2_ < 10; m2_++) rs += c2[t * 100 + mm * 10 + m2_];
    params[P_RSC2 + tid] = rs;
    params[P_F1 + tid] = (beta * s2 + 2.0f * alpha * hc2v) * (-ieps2);
  }
}

// --------- kernel 3: single-pair fused M + drift-folded Sinkhorn ------------
// lane = (node_s, t, k). Round-7 code verbatim (best measured ~257 us):
// in-iteration row load, pk-packed m-dimension, setprio around the
// dependency-chained phase. No cross-loop register rotation (compiler
// spills any such state -- proven rounds 0/3/6).
__global__ void __launch_bounds__(320, 6)
k_main(const half_t* __restrict__ xh, const float* __restrict__ tf_g,
       const float* __restrict__ c2_g, const int* __restrict__ nbc_g,
       const int* __restrict__ neigh_g, const float* __restrict__ params,
       const float* __restrict__ s2x_g, float* __restrict__ out) {
  __shared__ __align__(16) half_t tf_l[10 * TF_STRIDE];   // 12.96 KB
  __shared__ __align__(16) float c2_l[1000];              // 4 KB
  __shared__ __align__(16) float hc2_l[100];
  __shared__ __align__(16) float rsc2_l[100];
  __shared__ __align__(16) float F1_l[100];
  __shared__ __align__(16) float bsb_l[20][10][2];

  const int tid = threadIdx.x;
  const int node_s = tid / 160;
  const int s = tid % 160;
  const int t = s >> 4;
  const int k = s & 15;
  const bool k0 = (k == 0);
  const int grp = node_s * 10 + t;

  for (int i = tid; i < 6400; i += 320) {
    int tt = i / 640, rem = i - tt * 640;
    tf_l[tt * TF_STRIDE + rem] = (half_t)tf_g[i];
  }
  for (int i = tid; i < 1000; i += 320) c2_l[i] = c2_g[i];
  if (tid < 100) {
    hc2_l[tid]  = params[P_HC2 + tid];
    rsc2_l[tid] = params[P_RSC2 + tid];
    F1_l[tid]   = params[P_F1 + tid];
  }

  // wave-uniform constants -> SGPRs
  const float alpha = sgpr(params[P_ALPHA]);
  const float beta  = sgpr(params[P_BETA]);
  const float ieps2 = sgpr(params[P_IEPS2]);
  const float eps   = sgpr(params[P_EPS]);
  const float niep  = -ieps2;
  const float twoal = 2.0f * alpha;
  const float ctv10 = 0.2f * twoal * ieps2;    // = ctv*0.1 (drift-compensated)
  const float cab   = 2.0f * beta * ieps2;
  const float c_a2d = -eps * 0.69314718056f;   // Ab -> (beta*M + 2a*cc)
  const float twoal01 = 0.1f * twoal;
  const f32x2 cab2 = {cab, cab};
  const f32x2 ctv2 = {ctv10, ctv10};

  const int idx_c2 = t * 100 + ((k < 10) ? k : 9) * 10;   // C2[t][kc][*] base
  __syncthreads();

  const int kk = (k == 0) ? 0 : (k - 1);
  const half_t* tfb = &tf_l[t * TF_STRIDE];
  // prefetch pointer-chase chain for first pair
  int p = blockIdx.x;
  int nb_pf = nbc_g[2 * p + node_s];
  int nbr_pf = neigh_g[(2 * p + node_s) * KN + kk];

#pragma unroll 1
  for (; p < NPAIRS; p += gridDim.x) {
    const int v = 2 * p + node_s;
    const int nb = nb_pf;
    const int srcn = (k == 0) ? v : (kk < nb ? nbr_pf : 0);
    const float s2x = s2x_g[srcn];
    const uint4* xr = (const uint4*)(xh + (size_t)srcn * 64);

    // ---- issue the whole 128B row: 8 independent uint4 loads ----
    uint4 q[8];
#pragma unroll
    for (int r = 0; r < 8; r++) q[r] = xr[r];

    // prefetch next pair's chain (clamped; unused on last iteration)
    {
      int vn = 2 * (p + gridDim.x) + node_s;
      vn = vn < N_NODES ? vn : 0;
      nb_pf = nbc_g[vn];
      nbr_pf = neigh_g[vn * KN + kk];
    }

    // ---- per-lane M dot products: f16 row regs x LDS templates ----
    float acc[10];
#pragma unroll
    for (int m = 0; m < 10; m++) {
      float a = 0.0f;
#pragma unroll
      for (int ch = 0; ch < 4; ch++) {        // same per-acc order as before
        uint4 tqa = *(const uint4*)&tfb[m * 64 + ch * 16];
        uint4 tqb = *(const uint4*)&tfb[m * 64 + ch * 16 + 8];
        const uint4 qa = q[2 * ch];
        const uint4 qb = q[2 * ch + 1];
        a = fdot2(h2(tqa.x), h2(qa.x), a);
        a = fdot2(h2(tqa.y), h2(qa.y), a);
        a = fdot2(h2(tqa.z), h2(qa.z), a);
        a = fdot2(h2(tqa.w), h2(qa.w), a);
        a = fdot2(h2(tqb.x), h2(qb.x), a);
        a = fdot2(h2(tqb.y), h2(qb.y), a);
        a = fdot2(h2(tqb.z), h2(qb.z), a);
        a = fdot2(h2(tqb.w), h2(qb.w), a);
      }
      acc[m] = a;
    }

    __builtin_amdgcn_s_setprio(1);

    // ---- per-pair scalars ----
    const float inv = 1.0f / (float)(1 + nb);
    const float pk = (k <= nb) ? inv : 0.0f;
    const float hC1k = (k == 0) ? (float)nb * inv : ((k <= nb) ? inv : 0.0f);
    const float base = (beta * s2x + twoal * hC1k) * niep;
    const float ctm  = ctv10 * ((k == 0) ? (float)nb * inv : inv);
    const f32x2 base2 = {base, base};
    const f32x2 ctm2 = {ctm, ctm};

    f32x2 Ab2[5];
#pragma unroll
    for (int j = 0; j < 5; j++) {
      f32x2 f1v = *(const f32x2*)&F1_l[t * 10 + 2 * j];
      f32x2 av = {acc[2 * j], acc[2 * j + 1]};
      Ab2[j] = pk_fma(cab2, av, f1v + base2);
    }

    f32x2 K2[5], vv2[5];
    float u = 1.0f;
#pragma unroll
    for (int j = 0; j < 5; j++) { vv2[j][0] = 1.0f; vv2[j][1] = 1.0f; }

    // ---- outer 0: Tp = p (x) q -> tv from rowsum(C2) ----
#pragma unroll
    for (int j = 0; j < 5; j++) {
      f32x2 rs = *(const f32x2*)&rsc2_l[t * 10 + 2 * j];
      f32x2 arg = pk_fma(ctm2, rs, Ab2[j]);
      f32x2 Kv;
      Kv[0] = __builtin_amdgcn_exp2f(arg[0]);
      Kv[1] = __builtin_amdgcn_exp2f(arg[1]);
      K2[j] = Kv;
    }

#pragma unroll 1
    for (int o = 0; o < 3; o++) {
      // 5 drift-folded Sinkhorn iterations (m-pairs packed into pk ops)
#pragma unroll 1
      for (int it = 0; it < 5; it++) {
        f32x2 kv = {0.0f, 0.0f};
#pragma unroll
        for (int j = 0; j < 5; j++) kv = pk_fma(K2[j], vv2[j], kv);
        u = pk * __builtin_amdgcn_rcpf(kv[0] + kv[1]);
        f32x2 up = {u, u};
#pragma unroll
        for (int j = 0; j < 5; j++) {
          f32x2 Ku = pk_mul(K2[j], up);
          f32x2 nv;
          nv[0] = __builtin_amdgcn_rcpf(sum16(Ku[0]));
          nv[1] = __builtin_amdgcn_rcpf(sum16(Ku[1]));
          vv2[j] = nv;
        }
      }
      if (o == 2) break;
      // ---- site: recompute K from current Tp (tk' = 10*Tp) ----
      {
        const f32x2 up = {u, u};
        float B = 0.0f, SB = 0.0f;
#pragma unroll
        for (int j = 0; j < 5; j++) {
          float2 c2p = *(const float2*)&c2_l[idx_c2 + 2 * j];
          f32x2 tk2 = pk_mul(pk_mul(K2[j], vv2[j]), up);
          B  = fmaf(bcast16(tk2[0]), c2p.x, B);
          SB = fmaf(sum16(tk2[0]),   c2p.x, SB);
          B  = fmaf(bcast16(tk2[1]), c2p.y, B);
          SB = fmaf(sum16(tk2[1]),   c2p.y, SB);
        }
        if (k < 10) { bsb_l[grp][k][0] = B; bsb_l[grp][k][1] = SB; }
        __threadfence_block();
#pragma unroll
        for (int j = 0; j < 5; j++) {
          float4 bv = *(const float4*)&bsb_l[grp][2 * j][0];
          f32x2 tv2;
          tv2[0] = k0 ? (bv.y - bv.x) : bv.x;
          tv2[1] = k0 ? (bv.w - bv.z) : bv.z;
          f32x2 arg = pk_fma(ctv2, tv2, Ab2[j]);
          f32x2 Kv;
          Kv[0] = __builtin_amdgcn_exp2f(arg[0]);
          Kv[1] = __builtin_amdgcn_exp2f(arg[1]);
          K2[j] = Kv;
        }
        __threadfence_block();
      }
    }

    // ---- final: distance. coeff = c_a2d*Ab - alpha*cc - twoal*0.1*tv' ----
    {
      const f32x2 up = {u, u};
      f32x2 tkf[5];
      float B = 0.0f, SB = 0.0f;
#pragma unroll
      for (int j = 0; j < 5; j++) {
        float2 c2p = *(const float2*)&c2_l[idx_c2 + 2 * j];
        tkf[j] = pk_mul(pk_mul(K2[j], vv2[j]), up);
        B  = fmaf(bcast16(tkf[j][0]), c2p.x, B);
        SB = fmaf(sum16(tkf[j][0]),   c2p.x, SB);
        B  = fmaf(bcast16(tkf[j][1]), c2p.y, B);
        SB = fmaf(sum16(tkf[j][1]),   c2p.y, SB);
      }
      if (k < 10) { bsb_l[grp][k][0] = B; bsb_l[grp][k][1] = SB; }
      __threadfence_block();
      float dd = 0.0f;
#pragma unroll
      for (int j = 0; j < 5; j++) {
        float4 bv = *(const float4*)&bsb_l[grp][2 * j][0];
        float2 h2v = *(const float2*)&hc2_l[t * 10 + 2 * j];
        float tva = k0 ? (bv.y - bv.x) : bv.x;
        float tvb = k0 ? (bv.w - bv.z) : bv.z;
        float c1a = fmaf(alpha, hC1k + h2v.x, twoal01 * tva);
        float c1b = fmaf(alpha, hC1k + h2v.y, twoal01 * tvb);
        float coa = fmaf(c_a2d, Ab2[j][0], -c1a);
        float cob = fmaf(c_a2d, Ab2[j][1], -c1b);
        dd = fmaf(coa, tkf[j][0], dd);
        dd = fmaf(cob, tkf[j][1], dd);
      }
      __threadfence_block();
      dd = sum16(dd * 0.1f);
      if (k == 0) out[v * 10 + t] = dd;
    }

    __builtin_amdgcn_s_setprio(0);
  }
}

extern "C" void kernel_launch(void* const* d_in, const int* in_sizes, int n_in,
                              void* d_out, int out_size, void* d_ws, size_t ws_size,
                              hipStream_t stream) {
  const float* x  = (const float*)d_in[0];
  const int*   ei = (const int*)d_in[1];
  const float* c2 = (const float*)d_in[2];
  const float* tf = (const float*)d_in[3];
  const float* a0 = (const float*)d_in[4];
  float* out = (float*)d_out;
  char* ws = (char*)d_ws;
  int*    cnt    = (int*)(ws + OFF_CNT);
  int*    wct    = (int*)(ws + OFF_WCT);
  int*    flag   = (int*)(ws + OFF_FLAG);
  int*    padc   = (int*)(ws + OFF_PAD);
  int*    nbc    = (int*)(ws + OFF_NBC);
  float*  s2xh   = (float*)(ws + OFF_S2X);
  int*    neigh  = (int*)(ws + OFF_NEIGH);
  int*    buf    = (int*)(ws + OFF_BUF);
  half_t* xhalf  = (half_t*)(ws + OFF_BUF);   // overwrites buf after k_sel
  float*  params = (float*)(ws + OFF_PARAMS);
  float*  part   = (float*)(ws + OFF_PART);
  (void)in_sizes; (void)n_in; (void)out_size; (void)ws_size;

  hipMemsetAsync(ws, 0, MEMSET_LEN, stream);   // cnt+wct+flag+pad (one call)
  k_scatter<<<N_EDGES / 256, 256, 0, stream>>>(ei, cnt, buf);
  k_sel<<<SS_BLOCKS, 256, 0, stream>>>(ei, cnt, buf, nbc, neigh, wct, padc);
  k_pass<<<PB, 256, 0, stream>>>(x, xhalf, wct, padc, s2xh, part, flag,
                                 tf, c2, a0, params);
  k_main<<<GRID_MAIN, 320, 0, stream>>>(xhalf, tf, c2, nbc, neigh, params, s2xh, out);
}

// Round 9
// 364.313 us; speedup vs baseline: 1.1044x; 1.1044x over previous
//
#include <hip/hip_runtime.h>

#define N_NODES 20000
#define NPAIRS  10000
#define N_EDGES 320000
#define CAP     48
#define KN      15
#define GRID_MAIN 2500

typedef _Float16 half_t;
typedef _Float16 half2_t __attribute__((ext_vector_type(2)));
typedef float f32x2 __attribute__((ext_vector_type(2)));

// params float-index layout
#define P_ALPHA 0
#define P_BETA  1
#define P_IEPS2 2
#define P_EPS   3
#define P_HC2   16
#define P_RSC2  216
#define P_F1    316

// workspace byte offsets (single contiguous zero region up front)
#define OFF_CNT    0u             // 80 KB  (zeroed)
#define OFF_WCT    80000u         // 80 KB  (zeroed)
#define OFF_STATS  160000u        // 65 doubles (zeroed)
#define OFF_FLAG   160520u        // (zeroed)
#define OFF_PAD    160524u        // (zeroed)
#define MEMSET_LEN 160528u        // one memset covers cnt+wct+stats+flag+pad
#define OFF_NBC    160528u        // 80 KB
#define OFF_S2X    240528u        // 80 KB (written before read; no zeroing)
#define OFF_NEIGH  320528u        // 1.2 MB
#define OFF_BUF    1520528u       // 3.84 MB edge slots; xh (2.56 MB) overwrites
#define OFF_PARAMS 5360528u

// tf_l per-template stride (halfs): dword stride 324 = 4 (mod 32)
#define TF_STRIDE 648

// ---- 16-lane reduction via DPP row_ror adds: pure VALU ----
template<int CTRL>
__device__ __forceinline__ float dpp_add(float v) {
  int s = __builtin_bit_cast(int, v);
  int r = __builtin_amdgcn_update_dpp(0, s, CTRL, 0xF, 0xF, true);
  return v + __builtin_bit_cast(float, r);
}
__device__ __forceinline__ float sum16(float v) {
  v = dpp_add<0x128>(v);   // row_ror:8
  v = dpp_add<0x124>(v);   // row_ror:4
  v = dpp_add<0x122>(v);   // row_ror:2
  v = dpp_add<0x121>(v);   // row_ror:1
  return v;
}
// ds_swizzle imm BitMode 0x010: new_lane = lane&0x10 -> broadcast k=0 of group
__device__ __forceinline__ float bcast16(float v) {
  return __builtin_bit_cast(float,
      __builtin_amdgcn_ds_swizzle(__builtin_bit_cast(int, v), 0x010));
}
__device__ __forceinline__ float fdot2(half2_t a, half2_t b, float c) {
  return __builtin_amdgcn_fdot2(a, b, c, false);
}
__device__ __forceinline__ half2_t h2(unsigned int u) {
  return __builtin_bit_cast(half2_t, u);
}
// force a wave-uniform float into an SGPR
__device__ __forceinline__ float sgpr(float v) {
  return __builtin_bit_cast(float,
      __builtin_amdgcn_readfirstlane(__builtin_bit_cast(int, v)));
}
// ---- packed fp32 VALU ops: 2 independent IEEE fma/mul per instruction ----
__device__ __forceinline__ f32x2 pk_fma(f32x2 a, f32x2 b, f32x2 c) {
  f32x2 d;
  asm("v_pk_fma_f32 %0, %1, %2, %3" : "=v"(d) : "v"(a), "v"(b), "v"(c));
  return d;
}
__device__ __forceinline__ f32x2 pk_mul(f32x2 a, f32x2 b) {
  f32x2 d;
  asm("v_pk_mul_f32 %0, %1, %2" : "=v"(d) : "v"(a), "v"(b));
  return d;
}

// ---------------- kernel 1: scatter edge ids per source node ----------------
__global__ void k_scatter(const int* __restrict__ ei, int* __restrict__ cnt,
                          int* __restrict__ buf) {
  int e = blockIdx.x * blockDim.x + threadIdx.x;
  if (e >= N_EDGES) return;
  int s = ei[e];
  int slot = atomicAdd(&cnt[s], 1);
  if (slot < CAP) buf[s * CAP + slot] = e;
}

// ---- kernel 2: select 15 smallest edge ids, scatter neighbor weights ------
#define SS_BLOCKS 1250
__global__ void __launch_bounds__(256)
k_sel(const int* __restrict__ ei, const int* __restrict__ cnt,
      const int* __restrict__ buf, int* __restrict__ nbc_g,
      int* __restrict__ neigh, int* __restrict__ wct,
      int* __restrict__ padc) {
  const int lane = threadIdx.x & 63;
  const int wid = threadIdx.x >> 6;
  const int* dst = ei + N_EDGES;
  __shared__ int padsh;
  if (threadIdx.x == 0) padsh = 0;
  __syncthreads();
  int padacc = 0;

  for (int w = blockIdx.x * 4 + wid; w < N_NODES; w += SS_BLOCKS * 4) {
    int c = cnt[w];
    int cc = c < CAP ? c : CAP;
    int e = (lane < cc) ? buf[w * CAP + lane] : 0x7fffffff;
    int nb = c < KN ? c : KN;
    bool sel;
    if (cc <= KN) {
      sel = lane < cc;
    } else {
      int rank = 0;
      for (int j = 0; j < cc; j++) {      // cc is wave-uniform
        int ej = __shfl(e, j);
        rank += (ej < e) ? 1 : 0;
      }
      sel = (e != 0x7fffffff) && (rank < KN);  // distinct ids -> exactly 15
    }
    unsigned long long mask = __ballot(sel);
    if (sel) {
      int pos = __popcll(mask & ((1ull << lane) - 1ull));
      int d = dst[e];
      neigh[w * KN + pos] = d;
      atomicAdd(&wct[d], 1);             // neighbor-occurrence weight
    }
    if (lane == 0) { nbc_g[w] = nb; padacc += KN - nb; }
  }
  if (lane == 0 && padacc) atomicAdd(&padsh, padacc);
  __syncthreads();
  if (threadIdx.x == 0 && padsh) atomicAdd(padc, padsh);
}

// ---- kernel 2.5: ONE coalesced pass over x ---------------------------------
// Produces xh (f16 RTNE), s2xh, weighted eps-stats, then finalizes params.
#define PB 200
__global__ void __launch_bounds__(256)
k_pass(const float* __restrict__ x, half_t* __restrict__ xh,
       const int* __restrict__ wct, const int* __restrict__ padc,
       float* __restrict__ s2xh, double* __restrict__ stats,
       int* __restrict__ flag, const float* __restrict__ tf,
       const float* __restrict__ c2, const float* __restrict__ alpha0,
       float* __restrict__ params) {
  const int lane = threadIdx.x & 63;
  const int wid = threadIdx.x >> 6;
  const int tid = threadIdx.x;
  const int pad = *padc;
  float accx = 0.f, acc2 = 0.f;

  for (int n = blockIdx.x * 4 + wid; n < N_NODES; n += PB * 4) {
    float xv = x[n * 64 + lane];
    half_t hv = (half_t)xv;              // RTNE, matches k_main path
    xh[n * 64 + lane] = hv;
    float hf = (float)hv;
    float sq = hf * hf;
#pragma unroll
    for (int off = 32; off > 0; off >>= 1) sq += __shfl_xor(sq, off, 64);
    if (lane == 0) s2xh[n] = sq;
    float wt = (float)(1 + wct[n] + ((n == 0) ? pad : 0));
    accx = fmaf(wt, xv, accx);
    acc2 = fmaf(wt, xv * xv, acc2);
  }

  // ---- block reduction + global atomics (only PB=200 chains/address) ----
#pragma unroll
  for (int off = 32; off > 0; off >>= 1) acc2 += __shfl_xor(acc2, off, 64);
  __shared__ float redx[4][64];
  __shared__ float red2[4];
  __shared__ int lastsh;
  redx[wid][lane] = accx;
  if (lane == 0) red2[wid] = acc2;
  __syncthreads();
  if (tid < 64) {
    float s = redx[0][tid] + redx[1][tid] + redx[2][tid] + redx[3][tid];
    atomicAdd(&stats[1 + tid], (double)s);
  }
  if (tid == 0)
    atomicAdd(&stats[0], (double)(red2[0] + red2[1] + red2[2] + red2[3]));
  __syncthreads();
  if (tid == 0) {
    __threadfence();
    int old = atomicAdd(flag, 1);
    lastsh = (old == PB - 1) ? 1 : 0;
  }
  __syncthreads();
  if (!lastsh) return;
  __threadfence();   // acquire: all blocks' stats atomics visible
  // ------- finalize (runs once, in the last-finishing block) -------
  __shared__ float sh[4];
  if (tid < 64) {
    float s = 0.f, s2 = 0.f;
    for (int tm = 0; tm < 100; tm++) { float v = tf[tm * 64 + tid]; s += v; s2 += v * v; }
    double inv16N = 1.0 / (double)(N_NODES * 16);
    double cross = (stats[1 + tid] * inv16N) * ((double)s / 100.0);
    double B = (double)s2 / 100.0;
    double term = B - 2.0 * cross;
#pragma unroll
    for (int off = 32; off > 0; off >>= 1) term += __shfl_xor(term, off, 64);
    if (tid == 0) {
      double A = stats[0] * inv16N;
      double meanM = A + term;
      float eps = (float)(0.05 * meanM) + 1e-6f;
      float a0 = alpha0[0];
      float alpha = 1.f / (1.f + expf(-a0));
      params[P_ALPHA] = alpha;
      params[P_BETA]  = 1.f - alpha;
      params[P_IEPS2] = 1.4426950408889634f / eps;
      params[P_EPS]   = eps;
      sh[0] = alpha; sh[1] = 1.f - alpha; sh[2] = 1.4426950408889634f / eps;
    }
  }
  __syncthreads();
  if (tid < 100) {
    float alpha = sh[0], beta = sh[1], ieps2 = sh[2];
    int t = tid / 10, mm = tid % 10;
    float h = 0.f;
    for (int r = 0; r < 10; r++) { float cv = c2[t * 100 + mm * 10 + r]; h += cv * cv; }
    float hc2v = 0.1f * h;
    params[P_HC2 + tid] = hc2v;
    float s2 = 0.f;
    for (int f = 0; f < 64; f++) { float v = tf[tid * 64 + f]; s2 += v * v; }
    float rs = 0.f;
    for (int m2_ = 0; m2_ < 10; m2_++) rs += c2[t * 100 + mm * 10 + m2_];
    params[P_RSC2 + tid] = rs;
    params[P_F1 + tid] = (beta * s2 + 2.0f * alpha * hc2v) * (-ieps2);
  }
}

// --------- kernel 3: single-pair fused M + drift-folded Sinkhorn ------------
// lane = (node_s, t, k). Settled floor (~250-260 us): in-iteration row load,
// pk-packed m-dimension, setprio around the dependency-chained phase. No
// cross-loop register rotation (compiler spills any such state -- proven
// rounds 0/3/6).
__global__ void __launch_bounds__(320, 6)
k_main(const half_t* __restrict__ xh, const float* __restrict__ tf_g,
       const float* __restrict__ c2_g, const int* __restrict__ nbc_g,
       const int* __restrict__ neigh_g, const float* __restrict__ params,
       const float* __restrict__ s2x_g, float* __restrict__ out) {
  __shared__ __align__(16) half_t tf_l[10 * TF_STRIDE];   // 12.96 KB
  __shared__ __align__(16) float c2_l[1000];              // 4 KB
  __shared__ __align__(16) float hc2_l[100];
  __shared__ __align__(16) float rsc2_l[100];
  __shared__ __align__(16) float F1_l[100];
  __shared__ __align__(16) float bsb_l[20][10][2];

  const int tid = threadIdx.x;
  const int node_s = tid / 160;
  const int s = tid % 160;
  const int t = s >> 4;
  const int k = s & 15;
  const bool k0 = (k == 0);
  const int grp = node_s * 10 + t;

  for (int i = tid; i < 6400; i += 320) {
    int tt = i / 640, rem = i - tt * 640;
    tf_l[tt * TF_STRIDE + rem] = (half_t)tf_g[i];
  }
  for (int i = tid; i < 1000; i += 320) c2_l[i] = c2_g[i];
  if (tid < 100) {
    hc2_l[tid]  = params[P_HC2 + tid];
    rsc2_l[tid] = params[P_RSC2 + tid];
    F1_l[tid]   = params[P_F1 + tid];
  }

  // wave-uniform constants -> SGPRs
  const float alpha = sgpr(params[P_ALPHA]);
  const float beta  = sgpr(params[P_BETA]);
  const float ieps2 = sgpr(params[P_IEPS2]);
  const float eps   = sgpr(params[P_EPS]);
  const float niep  = -ieps2;
  const float twoal = 2.0f * alpha;
  const float ctv10 = 0.2f * twoal * ieps2;    // = ctv*0.1 (drift-compensated)
  const float cab   = 2.0f * beta * ieps2;
  const float c_a2d = -eps * 0.69314718056f;   // Ab -> (beta*M + 2a*cc)
  const float twoal01 = 0.1f * twoal;
  const f32x2 cab2 = {cab, cab};
  const f32x2 ctv2 = {ctv10, ctv10};

  const int idx_c2 = t * 100 + ((k < 10) ? k : 9) * 10;   // C2[t][kc][*] base
  __syncthreads();

  const int kk = (k == 0) ? 0 : (k - 1);
  const half_t* tfb = &tf_l[t * TF_STRIDE];
  // prefetch pointer-chase chain for first pair
  int p = blockIdx.x;
  int nb_pf = nbc_g[2 * p + node_s];
  int nbr_pf = neigh_g[(2 * p + node_s) * KN + kk];

#pragma unroll 1
  for (; p < NPAIRS; p += gridDim.x) {
    const int v = 2 * p + node_s;
    const int nb = nb_pf;
    const int srcn = (k == 0) ? v : (kk < nb ? nbr_pf : 0);
    const float s2x = s2x_g[srcn];
    const uint4* xr = (const uint4*)(xh + (size_t)srcn * 64);

    // ---- issue the whole 128B row: 8 independent uint4 loads ----
    uint4 q[8];
#pragma unroll
    for (int r = 0; r < 8; r++) q[r] = xr[r];

    // prefetch next pair's chain (clamped; unused on last iteration)
    {
      int vn = 2 * (p + gridDim.x) + node_s;
      vn = vn < N_NODES ? vn : 0;
      nb_pf = nbc_g[vn];
      nbr_pf = neigh_g[vn * KN + kk];
    }

    // ---- per-lane M dot products: f16 row regs x LDS templates ----
    float acc[10];
#pragma unroll
    for (int m = 0; m < 10; m++) {
      float a = 0.0f;
#pragma unroll
      for (int ch = 0; ch < 4; ch++) {        // same per-acc order as before
        uint4 tqa = *(const uint4*)&tfb[m * 64 + ch * 16];
        uint4 tqb = *(const uint4*)&tfb[m * 64 + ch * 16 + 8];
        const uint4 qa = q[2 * ch];
        const uint4 qb = q[2 * ch + 1];
        a = fdot2(h2(tqa.x), h2(qa.x), a);
        a = fdot2(h2(tqa.y), h2(qa.y), a);
        a = fdot2(h2(tqa.z), h2(qa.z), a);
        a = fdot2(h2(tqa.w), h2(qa.w), a);
        a = fdot2(h2(tqb.x), h2(qb.x), a);
        a = fdot2(h2(tqb.y), h2(qb.y), a);
        a = fdot2(h2(tqb.z), h2(qb.z), a);
        a = fdot2(h2(tqb.w), h2(qb.w), a);
      }
      acc[m] = a;
    }

    __builtin_amdgcn_s_setprio(1);

    // ---- per-pair scalars ----
    const float inv = 1.0f / (float)(1 + nb);
    const float pk = (k <= nb) ? inv : 0.0f;
    const float hC1k = (k == 0) ? (float)nb * inv : ((k <= nb) ? inv : 0.0f);
    const float base = (beta * s2x + twoal * hC1k) * niep;
    const float ctm  = ctv10 * ((k == 0) ? (float)nb * inv : inv);
    const f32x2 base2 = {base, base};
    const f32x2 ctm2 = {ctm, ctm};

    f32x2 Ab2[5];
#pragma unroll
    for (int j = 0; j < 5; j++) {
      f32x2 f1v = *(const f32x2*)&F1_l[t * 10 + 2 * j];
      f32x2 av = {acc[2 * j], acc[2 * j + 1]};
      Ab2[j] = pk_fma(cab2, av, f1v + base2);
    }

    f32x2 K2[5], vv2[5];
    float u = 1.0f;
#pragma unroll
    for (int j = 0; j < 5; j++) { vv2[j][0] = 1.0f; vv2[j][1] = 1.0f; }

    // ---- outer 0: Tp = p (x) q -> tv from rowsum(C2) ----
#pragma unroll
    for (int j = 0; j < 5; j++) {
      f32x2 rs = *(const f32x2*)&rsc2_l[t * 10 + 2 * j];
      f32x2 arg = pk_fma(ctm2, rs, Ab2[j]);
      f32x2 Kv;
      Kv[0] = __builtin_amdgcn_exp2f(arg[0]);
      Kv[1] = __builtin_amdgcn_exp2f(arg[1]);
      K2[j] = Kv;
    }

#pragma unroll 1
    for (int o = 0; o < 3; o++) {
      // 5 drift-folded Sinkhorn iterations (m-pairs packed into pk ops)
#pragma unroll 1
      for (int it = 0; it < 5; it++) {
        f32x2 kv = {0.0f, 0.0f};
#pragma unroll
        for (int j = 0; j < 5; j++) kv = pk_fma(K2[j], vv2[j], kv);
        u = pk * __builtin_amdgcn_rcpf(kv[0] + kv[1]);
        f32x2 up = {u, u};
#pragma unroll
        for (int j = 0; j < 5; j++) {
          f32x2 Ku = pk_mul(K2[j], up);
          f32x2 nv;
          nv[0] = __builtin_amdgcn_rcpf(sum16(Ku[0]));
          nv[1] = __builtin_amdgcn_rcpf(sum16(Ku[1]));
          vv2[j] = nv;
        }
      }
      if (o == 2) break;
      // ---- site: recompute K from current Tp (tk' = 10*Tp) ----
      {
        const f32x2 up = {u, u};
        float B = 0.0f, SB = 0.0f;
#pragma unroll
        for (int j = 0; j < 5; j++) {
          float2 c2p = *(const float2*)&c2_l[idx_c2 + 2 * j];
          f32x2 tk2 = pk_mul(pk_mul(K2[j], vv2[j]), up);
          B  = fmaf(bcast16(tk2[0]), c2p.x, B);
          SB = fmaf(sum16(tk2[0]),   c2p.x, SB);
          B  = fmaf(bcast16(tk2[1]), c2p.y, B);
          SB = fmaf(sum16(tk2[1]),   c2p.y, SB);
        }
        if (k < 10) { bsb_l[grp][k][0] = B; bsb_l[grp][k][1] = SB; }
        __threadfence_block();
#pragma unroll
        for (int j = 0; j < 5; j++) {
          float4 bv = *(const float4*)&bsb_l[grp][2 * j][0];
          f32x2 tv2;
          tv2[0] = k0 ? (bv.y - bv.x) : bv.x;
          tv2[1] = k0 ? (bv.w - bv.z) : bv.z;
          f32x2 arg = pk_fma(ctv2, tv2, Ab2[j]);
          f32x2 Kv;
          Kv[0] = __builtin_amdgcn_exp2f(arg[0]);
          Kv[1] = __builtin_amdgcn_exp2f(arg[1]);
          K2[j] = Kv;
        }
        __threadfence_block();
      }
    }

    // ---- final: distance. coeff = c_a2d*Ab - alpha*cc - twoal*0.1*tv' ----
    {
      const f32x2 up = {u, u};
      f32x2 tkf[5];
      float B = 0.0f, SB = 0.0f;
#pragma unroll
      for (int j = 0; j < 5; j++) {
        float2 c2p = *(const float2*)&c2_l[idx_c2 + 2 * j];
        tkf[j] = pk_mul(pk_mul(K2[j], vv2[j]), up);
        B  = fmaf(bcast16(tkf[j][0]), c2p.x, B);
        SB = fmaf(sum16(tkf[j][0]),   c2p.x, SB);
        B  = fmaf(bcast16(tkf[j][1]), c2p.y, B);
        SB = fmaf(sum16(tkf[j][1]),   c2p.y, SB);
      }
      if (k < 10) { bsb_l[grp][k][0] = B; bsb_l[grp][k][1] = SB; }
      __threadfence_block();
      float dd = 0.0f;
#pragma unroll
      for (int j = 0; j < 5; j++) {
        float4 bv = *(const float4*)&bsb_l[grp][2 * j][0];
        float2 h2v = *(const float2*)&hc2_l[t * 10 + 2 * j];
        float tva = k0 ? (bv.y - bv.x) : bv.x;
        float tvb = k0 ? (bv.w - bv.z) : bv.z;
        float c1a = fmaf(alpha, hC1k + h2v.x, twoal01 * tva);
        float c1b = fmaf(alpha, hC1k + h2v.y, twoal01 * tvb);
        float coa = fmaf(c_a2d, Ab2[j][0], -c1a);
        float cob = fmaf(c_a2d, Ab2[j][1], -c1b);
        dd = fmaf(coa, tkf[j][0], dd);
        dd = fmaf(cob, tkf[j][1], dd);
      }
      __threadfence_block();
      dd = sum16(dd * 0.1f);
      if (k == 0) out[v * 10 + t] = dd;
    }

    __builtin_amdgcn_s_setprio(0);
  }
}

extern "C" void kernel_launch(void* const* d_in, const int* in_sizes, int n_in,
                              void* d_out, int out_size, void* d_ws, size_t ws_size,
                              hipStream_t stream) {
  const float* x  = (const float*)d_in[0];
  const int*   ei = (const int*)d_in[1];
  const float* c2 = (const float*)d_in[2];
  const float* tf = (const float*)d_in[3];
  const float* a0 = (const float*)d_in[4];
  float* out = (float*)d_out;
  char* ws = (char*)d_ws;
  int*    cnt    = (int*)(ws + OFF_CNT);
  int*    wct    = (int*)(ws + OFF_WCT);
  double* stats  = (double*)(ws + OFF_STATS);
  int*    flag   = (int*)(ws + OFF_FLAG);
  int*    padc   = (int*)(ws + OFF_PAD);
  int*    nbc    = (int*)(ws + OFF_NBC);
  float*  s2xh   = (float*)(ws + OFF_S2X);
  int*    neigh  = (int*)(ws + OFF_NEIGH);
  int*    buf    = (int*)(ws + OFF_BUF);
  half_t* xhalf  = (half_t*)(ws + OFF_BUF);   // overwrites buf after k_sel
  float*  params = (float*)(ws + OFF_PARAMS);
  (void)in_sizes; (void)n_in; (void)out_size; (void)ws_size;

  hipMemsetAsync(ws, 0, MEMSET_LEN, stream);   // cnt+wct+stats+flag+pad (one call)
  k_scatter<<<N_EDGES / 256, 256, 0, stream>>>(ei, cnt, buf);
  k_sel<<<SS_BLOCKS, 256, 0, stream>>>(ei, cnt, buf, nbc, neigh, wct, padc);
  k_pass<<<PB, 256, 0, stream>>>(x, xhalf, wct, padc, s2xh, stats, flag,
                                 tf, c2, a0, params);
  k_main<<<GRID_MAIN, 320, 0, stream>>>(xhalf, tf, c2, nbc, neigh, params, s2xh, out);
}